// Round 3
// baseline (155.018 us; speedup 1.0000x reference)
//
#include <hip/hip_runtime.h>

#define HH 64
#define WW 64
#define NN 4096
#define DZc 128
#define KS 8
#define BK 64
#define NKT (NN / KS / BK)        // 8 k-tiles per block
#define CELLS 2097152             // 4*64*64*128 output floats
#define ZT_BYTES (4ull * 128 * 4096 * 2ull)            // packed zT f16: 4 MB
#define WS_NEED (ZT_BYTES + 8ull * CELLS * 2ull)       // zT + f16 partials: 36 MB

typedef __fp16 v2fp16 __attribute__((ext_vector_type(2)));
typedef _Float16 v4h __attribute__((ext_vector_type(4)));
typedef _Float16 v8h __attribute__((ext_vector_type(8)));
typedef float v16f __attribute__((ext_vector_type(16)));
typedef double v2d __attribute__((ext_vector_type(2)));

__device__ __forceinline__ unsigned pk16(float lo, float hi){
  union { v2fp16 h; unsigned u; } c;
  c.h = __builtin_amdgcn_cvt_pkrtz(lo, hi);
  return c.u;
}
__device__ __forceinline__ float fexp2(float x){ return __builtin_amdgcn_exp2f(x); }

__global__ void init_out_kernel(const float4* __restrict__ zc_on,
                                const int* __restrict__ ignore,
                                float4* __restrict__ out){
  int i = blockIdx.x * blockDim.x + threadIdx.x;
  float4 v = zc_on[i];
  if (ignore[0]) { v.x = 0.f; v.y = 0.f; v.z = 0.f; v.w = 0.f; }
  out[i] = v;
}

// transpose+pack z once: f32 [B][N][128] -> f16 zT [B][128][N].
__global__ __launch_bounds__(256, 4)
void prepack_kernel(const float* __restrict__ zc_off, _Float16* __restrict__ zt_g){
  __shared__ unsigned tt[128 * 34];   // [d][n-pair] dwords, row stride 34 dw (68 f16)
  const int bidx = blockIdx.x;
  const int b  = bidx >> 6;
  const int n0 = (bidx & 63) * 64;
  const int t  = threadIdx.x;

  const int np = t >> 3;
  const int d0 = (t & 7) * 16;
  const float* r0 = zc_off + ((size_t)(b * NN + n0 + 2 * np)) * DZc + d0;
  float4 a[4], c[4];
  #pragma unroll
  for (int i = 0; i < 4; ++i){
    a[i] = *(const float4*)&r0[4 * i];
    c[i] = *(const float4*)&r0[DZc + 4 * i];
  }
  const float* af = (const float*)a;
  const float* cf = (const float*)c;
  #pragma unroll
  for (int j = 0; j < 16; ++j)
    tt[(d0 + j) * 34 + np] = pk16(af[j], cf[j]);

  __syncthreads();

  const int d  = t >> 1;
  const int nh = t & 1;
  const unsigned* rr = tt + d * 34 + nh * 16;
  _Float16* w = zt_g + ((size_t)(b * DZc + d)) * NN + n0 + nh * 32;
  double v[8];
  #pragma unroll
  for (int j = 0; j < 8; ++j) v[j] = *(const double*)&rr[2 * j];
  #pragma unroll
  for (int j = 0; j < 4; ++j){
    v2d s; s[0] = v[2 * j]; s[1] = v[2 * j + 1];
    *(v2d*)&w[8 * j] = s;
  }
}

// sum 8 f16 K-split partials + zc_on -> out (coalesced v4h loads, float4 store)
__global__ void reduce_kernel(const v4h* __restrict__ part,
                              const float4* __restrict__ zc_on,
                              const int* __restrict__ ignore,
                              float4* __restrict__ out){
  int i = blockIdx.x * blockDim.x + threadIdx.x;
  float4 s = zc_on[i];
  if (ignore[0]) { s.x = 0.f; s.y = 0.f; s.z = 0.f; s.w = 0.f; }
  #pragma unroll
  for (int ks = 0; ks < KS; ++ks){
    v4h p = part[(size_t)ks * (CELLS / 4) + i];
    s.x += (float)p[0]; s.y += (float)p[1]; s.z += (float)p[2]; s.w += (float)p[3];
  }
  out[i] = s;
}

// Grid: 512 blocks = ks(8, HIGH bits) x b(4) x mt(16).
// Block: 256 thr = 4 waves; BM=256 (32iy x 8ix), BD=128, BK=64, 8 k-tiles.
// DIAGNOSTIC (this round): launched 3x back-to-back (idempotent partial writes)
// so dur_us = base + 2*G reveals the gemm's true dispatch time G, since the
// harness fill dispatches (45-51us) crowd every profiler top-5 slot.
template<bool PRE>
__global__ __launch_bounds__(256, 2)
void setconv_gemm_kernel(const float* __restrict__ xc_off,
                         const float* __restrict__ xc_on,
                         const float* __restrict__ zc_off,
                         const _Float16* __restrict__ zpack,
                         const float* __restrict__ lsp,
                         _Float16* __restrict__ part,
                         float* __restrict__ out)
{
  __shared__ unsigned short zt[2][128][68];  // Z^T f16 [d][k], stride 34 dw
  __shared__ unsigned short gt[2][40][72];   // f16 g-tables, stride 36 dw

  const int tid = threadIdx.x;
  const int bid = blockIdx.x;
  const int ks  = bid >> 6;
  const int bm  = bid & 63;
  const int b   = bm >> 4;
  const int mt  = bm & 15;
  const int iy0 = (mt >> 3) * 32;
  const int ix0 = (mt & 7) * 8;
  const int nbase = ks * (NN / KS);

  const float lsy = 1e-5f + log1pf(expf(lsp[0]));
  const float lsx = 1e-5f + log1pf(expf(lsp[1]));
  const float LOG2E = 1.44269504088896340736f;
  const float ay = -0.5f * LOG2E / (lsy * lsy);
  const float ax = -0.5f * LOG2E / (lsx * lsx);

  const int gp = tid & 31;
  const int gr = tid >> 5;
  float gc[5], ga[5];
  #pragma unroll
  for (int i = 0; i < 5; ++i){
    int row = gr + 8 * i;
    if (row < 32){ gc[i] = xc_on[((b * HH + iy0 + row) * WW) * 2];        ga[i] = ay; }
    else         { gc[i] = xc_on[(b * HH * WW + ix0 + row - 32) * 2 + 1]; ga[i] = ax; }
  }

  const int zd  = (tid & 63) | (((tid >> 6) & 1) << 6);
  const int zkh = tid >> 7;
  const _Float16* ztg = PRE ? (zpack + ((size_t)(b * DZc + zd)) * NN + nbase + zkh * 32)
                            : (const _Float16*)nullptr;

  const int lane = tid & 63;
  const int wv  = tid >> 6;
  const int l31 = lane & 31;
  const int lh  = lane >> 5;
  const int gxr = 32 + (l31 & 7);
  const int gyr = wv * 8 + (l31 >> 3);

  v16f acc[2][4];
  #pragma unroll
  for (int m = 0; m < 2; ++m)
    #pragma unroll
    for (int d = 0; d < 4; ++d)
      #pragma unroll
      for (int r = 0; r < 16; ++r)
        acc[m][d][r] = 0.f;

  const float* xb = xc_off + (size_t)b * NN * 2;
  const float* zb = zc_off + (size_t)b * NN * DZc;

  {
    const int n0 = nbase;
    float4 xq = *(const float4*)&xb[(size_t)(n0 + 2 * gp) * 2];
    unsigned* gw = (unsigned*)&gt[0][0][0];
    #pragma unroll
    for (int i = 0; i < 5; ++i){
      int row = gr + 8 * i;
      float s0 = (row < 32) ? xq.x : xq.y;
      float s1 = (row < 32) ? xq.z : xq.w;
      float d0 = gc[i] - s0, d1 = gc[i] - s1;
      gw[row * 36 + gp] = pk16(fexp2(ga[i] * d0 * d0), fexp2(ga[i] * d1 * d1));
    }
    if (PRE){
      #pragma unroll
      for (int i = 0; i < 4; ++i){
        union { v8h v; double d[2]; } u;
        u.v = *(const v8h*)&ztg[8 * i];
        *(double*)&zt[0][zd][zkh * 32 + 8 * i]     = u.d[0];
        *(double*)&zt[0][zd][zkh * 32 + 8 * i + 4] = u.d[1];
      }
    } else {
      float zv[32];
      #pragma unroll
      for (int i = 0; i < 32; ++i)
        zv[i] = zb[(size_t)(n0 + zkh * 32 + i) * DZc + zd];
      #pragma unroll
      for (int j = 0; j < 8; ++j){
        union { unsigned u[2]; double d; } w;
        w.u[0] = pk16(zv[4 * j],     zv[4 * j + 1]);
        w.u[1] = pk16(zv[4 * j + 2], zv[4 * j + 3]);
        *(double*)&zt[0][zd][zkh * 32 + 4 * j] = w.d;
      }
    }
  }
  __syncthreads();

  #pragma unroll 1
  for (int kt = 0; kt < NKT; ++kt){
    const int buf  = kt & 1;
    const int nbuf = buf ^ 1;
    const bool have_next = (kt + 1 < NKT);
    const int n1 = nbase + (kt + 1) * BK;

    v8h zrn[4];
    float zv[32];
    float4 xq_n = (float4){0.f, 0.f, 0.f, 0.f};
    if (have_next){
      if (PRE){
        #pragma unroll
        for (int i = 0; i < 4; ++i)
          zrn[i] = *(const v8h*)&ztg[(kt + 1) * BK + 8 * i];
      } else {
        #pragma unroll
        for (int i = 0; i < 32; ++i)
          zv[i] = zb[(size_t)(n1 + zkh * 32 + i) * DZc + zd];
      }
      xq_n = *(const float4*)&xb[(size_t)(n1 + 2 * gp) * 2];
    }

    #pragma unroll
    for (int kstep = 0; kstep < 4; ++kstep){
      const int k0 = kstep * 16 + lh * 8;
      const v8h xu = *(const v8h*)&gt[buf][gxr][k0];
      v8h bfr[4];
      #pragma unroll
      for (int dtl = 0; dtl < 4; ++dtl){
        union { v4h h[2]; v8h v; } zu;
        zu.h[0] = *(const v4h*)&zt[buf][dtl * 32 + l31][k0];
        zu.h[1] = *(const v4h*)&zt[buf][dtl * 32 + l31][k0 + 4];
        bfr[dtl] = zu.v;
      }
      #pragma unroll
      for (int mtl = 0; mtl < 2; ++mtl){
        const v8h yu = *(const v8h*)&gt[buf][gyr + mtl * 4][k0];
        v8h av = yu * xu;   // 4x v_pk_mul_f16
        #pragma unroll
        for (int dtl = 0; dtl < 4; ++dtl)
          acc[mtl][dtl] = __builtin_amdgcn_mfma_f32_32x32x16_f16(av, bfr[dtl], acc[mtl][dtl], 0, 0, 0);
      }
    }

    if (have_next){
      if (PRE){
        #pragma unroll
        for (int i = 0; i < 4; ++i){
          union { v8h v; double d[2]; } u;
          u.v = zrn[i];
          *(double*)&zt[nbuf][zd][zkh * 32 + 8 * i]     = u.d[0];
          *(double*)&zt[nbuf][zd][zkh * 32 + 8 * i + 4] = u.d[1];
        }
      } else {
        #pragma unroll
        for (int j = 0; j < 8; ++j){
          union { unsigned u[2]; double d; } w;
          w.u[0] = pk16(zv[4 * j],     zv[4 * j + 1]);
          w.u[1] = pk16(zv[4 * j + 2], zv[4 * j + 3]);
          *(double*)&zt[nbuf][zd][zkh * 32 + 4 * j] = w.d;
        }
      }
      unsigned* gw = (unsigned*)&gt[nbuf][0][0];
      #pragma unroll
      for (int i = 0; i < 5; ++i){
        int row = gr + 8 * i;
        float s0 = (row < 32) ? xq_n.x : xq_n.y;
        float s1 = (row < 32) ? xq_n.z : xq_n.w;
        float d0 = gc[i] - s0, d1 = gc[i] - s1;
        gw[row * 36 + gp] = pk16(fexp2(ga[i] * d0 * d0), fexp2(ga[i] * d1 * d1));
      }
    }
    __syncthreads();
  }

  // ---- epilogue
  if (part){
    _Float16* pw = part + (size_t)ks * CELLS;
    #pragma unroll
    for (int mtl = 0; mtl < 2; ++mtl)
      #pragma unroll
      for (int dtl = 0; dtl < 4; ++dtl){
        const int d = dtl * 32 + l31;
        #pragma unroll
        for (int reg = 0; reg < 16; ++reg){
          const int row = (reg & 3) + 8 * (reg >> 2) + 4 * lh;
          const int m = wv * 64 + mtl * 32 + row;
          const int iy = iy0 + (m >> 3);
          const int ix = ix0 + (m & 7);
          pw[((b * HH + iy) * WW + ix) * DZc + d] = (_Float16)acc[mtl][dtl][reg];
        }
      }
  } else {
    #pragma unroll
    for (int mtl = 0; mtl < 2; ++mtl)
      #pragma unroll
      for (int dtl = 0; dtl < 4; ++dtl){
        const int d = dtl * 32 + l31;
        #pragma unroll
        for (int reg = 0; reg < 16; ++reg){
          const int row = (reg & 3) + 8 * (reg >> 2) + 4 * lh;
          const int m = wv * 64 + mtl * 32 + row;
          const int iy = iy0 + (m >> 3);
          const int ix = ix0 + (m & 7);
          unsafeAtomicAdd(&out[((b * HH + iy) * WW + ix) * DZc + d], acc[mtl][dtl][reg]);
        }
      }
  }
}

extern "C" void kernel_launch(void* const* d_in, const int* in_sizes, int n_in,
                              void* d_out, int out_size, void* d_ws, size_t ws_size,
                              hipStream_t stream){
  const float* xc_off = (const float*)d_in[0];
  const float* xc_on  = (const float*)d_in[1];
  const float* zc_off = (const float*)d_in[2];
  const float* zc_on  = (const float*)d_in[3];
  const float* lsp    = (const float*)d_in[4];
  const int*   ign    = (const int*)d_in[5];
  float* out = (float*)d_out;

  if (ws_size >= WS_NEED){
    _Float16* zpack = (_Float16*)d_ws;
    _Float16* part  = (_Float16*)((char*)d_ws + ZT_BYTES);
    prepack_kernel<<<4 * 64, 256, 0, stream>>>(zc_off, zpack);
    // DIAGNOSTIC: 3 identical idempotent launches. dur_us - base = 2*G.
    setconv_gemm_kernel<true><<<KS * 64, 256, 0, stream>>>(xc_off, xc_on, zc_off, zpack, lsp, part, out);
    setconv_gemm_kernel<true><<<KS * 64, 256, 0, stream>>>(xc_off, xc_on, zc_off, zpack, lsp, part, out);
    setconv_gemm_kernel<true><<<KS * 64, 256, 0, stream>>>(xc_off, xc_on, zc_off, zpack, lsp, part, out);
    reduce_kernel<<<CELLS / 4 / 256, 256, 0, stream>>>((const v4h*)part, (const float4*)zc_on, ign, (float4*)out);
  } else {
    init_out_kernel<<<out_size / 1024, 256, 0, stream>>>((const float4*)zc_on, ign, (float4*)out);
    setconv_gemm_kernel<false><<<KS * 64, 256, 0, stream>>>(xc_off, xc_on, zc_off, nullptr, lsp, nullptr, out);
  }
}

// Round 4
// 143.588 us; speedup vs baseline: 1.0796x; 1.0796x over previous
//
#include <hip/hip_runtime.h>

#define HH 64
#define WW 64
#define NN 4096
#define DZc 128
#define KS 8
#define BK 64
#define NKT (NN / KS / BK)        // 8 k-tiles per block
#define CELLS 2097152             // 4*64*64*128 output floats
#define ZT_BYTES (4ull * 128 * 4096 * 2ull)            // packed zT f16: 4 MB

typedef __fp16 v2fp16 __attribute__((ext_vector_type(2)));
typedef _Float16 v4h __attribute__((ext_vector_type(4)));
typedef _Float16 v8h __attribute__((ext_vector_type(8)));
typedef float v16f __attribute__((ext_vector_type(16)));
typedef double v2d __attribute__((ext_vector_type(2)));

__device__ __forceinline__ unsigned pk16(float lo, float hi){
  union { v2fp16 h; unsigned u; } c;
  c.h = __builtin_amdgcn_cvt_pkrtz(lo, hi);
  return c.u;
}
__device__ __forceinline__ float fexp2(float x){ return __builtin_amdgcn_exp2f(x); }

// out = zc_on (or 0 if ignore). Grid sized from CELLS (2048 blocks), NOT out_size.
__global__ __launch_bounds__(256, 8)
void init_out_kernel(const float4* __restrict__ zc_on,
                     const int* __restrict__ ignore,
                     float4* __restrict__ out){
  int i = blockIdx.x * blockDim.x + threadIdx.x;
  float4 v = zc_on[i];
  if (ignore[0]) { v.x = 0.f; v.y = 0.f; v.z = 0.f; v.w = 0.f; }
  out[i] = v;
}

// transpose+pack z once: f32 [B][N][128] -> f16 zT [B][128][N].
__global__ __launch_bounds__(256, 4)
void prepack_kernel(const float* __restrict__ zc_off, _Float16* __restrict__ zt_g){
  __shared__ unsigned tt[128 * 34];   // [d][n-pair] dwords, row stride 34 dw (68 f16)
  const int bidx = blockIdx.x;
  const int b  = bidx >> 6;
  const int n0 = (bidx & 63) * 64;
  const int t  = threadIdx.x;

  const int np = t >> 3;
  const int d0 = (t & 7) * 16;
  const float* r0 = zc_off + ((size_t)(b * NN + n0 + 2 * np)) * DZc + d0;
  float4 a[4], c[4];
  #pragma unroll
  for (int i = 0; i < 4; ++i){
    a[i] = *(const float4*)&r0[4 * i];
    c[i] = *(const float4*)&r0[DZc + 4 * i];
  }
  const float* af = (const float*)a;
  const float* cf = (const float*)c;
  #pragma unroll
  for (int j = 0; j < 16; ++j)
    tt[(d0 + j) * 34 + np] = pk16(af[j], cf[j]);

  __syncthreads();

  const int d  = t >> 1;
  const int nh = t & 1;
  const unsigned* rr = tt + d * 34 + nh * 16;
  _Float16* w = zt_g + ((size_t)(b * DZc + d)) * NN + n0 + nh * 32;
  double v[8];
  #pragma unroll
  for (int j = 0; j < 8; ++j) v[j] = *(const double*)&rr[2 * j];
  #pragma unroll
  for (int j = 0; j < 4; ++j){
    v2d s; s[0] = v[2 * j]; s[1] = v[2 * j + 1];
    *(v2d*)&w[8 * j] = s;
  }
}

// Grid: 512 blocks = ks(8, HIGH bits) x b(4) x mt(16).
// Block: 256 thr = 4 waves; BM=256 (32iy x 8ix), BD=128, BK=64, 8 k-tiles.
// Epilogue: direct f32 atomicAdd into zc_on-initialized out (split-K via atomics).
// XCD-coherence: the 8 ks-writers of a tile share bid mod 8 -> same XCD L2.
// This removes the 32MB partial store + 48MB reduce pass of the old scheme.
template<bool PRE>
__global__ __launch_bounds__(256, 2)
void setconv_gemm_kernel(const float* __restrict__ xc_off,
                         const float* __restrict__ xc_on,
                         const float* __restrict__ zc_off,
                         const _Float16* __restrict__ zpack,
                         const float* __restrict__ lsp,
                         float* __restrict__ out)
{
  __shared__ unsigned short zt[2][128][68];  // Z^T f16 [d][k], stride 34 dw (0 conflicts measured)
  __shared__ unsigned short gt[2][40][72];   // f16 g-tables, stride 36 dw

  const int tid = threadIdx.x;
  const int bid = blockIdx.x;
  const int ks  = bid >> 6;
  const int bm  = bid & 63;
  const int b   = bm >> 4;
  const int mt  = bm & 15;
  const int iy0 = (mt >> 3) * 32;
  const int ix0 = (mt & 7) * 8;
  const int nbase = ks * (NN / KS);

  const float lsy = 1e-5f + log1pf(expf(lsp[0]));
  const float lsx = 1e-5f + log1pf(expf(lsp[1]));
  const float LOG2E = 1.44269504088896340736f;
  const float ay = -0.5f * LOG2E / (lsy * lsy);
  const float ax = -0.5f * LOG2E / (lsx * lsx);

  const int gp = tid & 31;
  const int gr = tid >> 5;
  float gc[5], ga[5];
  #pragma unroll
  for (int i = 0; i < 5; ++i){
    int row = gr + 8 * i;
    if (row < 32){ gc[i] = xc_on[((b * HH + iy0 + row) * WW) * 2];        ga[i] = ay; }
    else         { gc[i] = xc_on[(b * HH * WW + ix0 + row - 32) * 2 + 1]; ga[i] = ax; }
  }

  const int zd  = (tid & 63) | (((tid >> 6) & 1) << 6);
  const int zkh = tid >> 7;
  const _Float16* ztg = PRE ? (zpack + ((size_t)(b * DZc + zd)) * NN + nbase + zkh * 32)
                            : (const _Float16*)nullptr;

  const int lane = tid & 63;
  const int wv  = tid >> 6;
  const int l31 = lane & 31;
  const int lh  = lane >> 5;
  const int gxr = 32 + (l31 & 7);
  const int gyr = wv * 8 + (l31 >> 3);

  v16f acc[2][4];
  #pragma unroll
  for (int m = 0; m < 2; ++m)
    #pragma unroll
    for (int d = 0; d < 4; ++d)
      #pragma unroll
      for (int r = 0; r < 16; ++r)
        acc[m][d][r] = 0.f;

  const float* xb = xc_off + (size_t)b * NN * 2;
  const float* zb = zc_off + (size_t)b * NN * DZc;

  {
    const int n0 = nbase;
    float4 xq = *(const float4*)&xb[(size_t)(n0 + 2 * gp) * 2];
    unsigned* gw = (unsigned*)&gt[0][0][0];
    #pragma unroll
    for (int i = 0; i < 5; ++i){
      int row = gr + 8 * i;
      float s0 = (row < 32) ? xq.x : xq.y;
      float s1 = (row < 32) ? xq.z : xq.w;
      float d0 = gc[i] - s0, d1 = gc[i] - s1;
      gw[row * 36 + gp] = pk16(fexp2(ga[i] * d0 * d0), fexp2(ga[i] * d1 * d1));
    }
    if (PRE){
      #pragma unroll
      for (int i = 0; i < 4; ++i){
        union { v8h v; double d[2]; } u;
        u.v = *(const v8h*)&ztg[8 * i];
        *(double*)&zt[0][zd][zkh * 32 + 8 * i]     = u.d[0];
        *(double*)&zt[0][zd][zkh * 32 + 8 * i + 4] = u.d[1];
      }
    } else {
      float zv[32];
      #pragma unroll
      for (int i = 0; i < 32; ++i)
        zv[i] = zb[(size_t)(n0 + zkh * 32 + i) * DZc + zd];
      #pragma unroll
      for (int j = 0; j < 8; ++j){
        union { unsigned u[2]; double d; } w;
        w.u[0] = pk16(zv[4 * j],     zv[4 * j + 1]);
        w.u[1] = pk16(zv[4 * j + 2], zv[4 * j + 3]);
        *(double*)&zt[0][zd][zkh * 32 + 4 * j] = w.d;
      }
    }
  }
  __syncthreads();

  #pragma unroll 1
  for (int kt = 0; kt < NKT; ++kt){
    const int buf  = kt & 1;
    const int nbuf = buf ^ 1;
    const bool have_next = (kt + 1 < NKT);
    const int n1 = nbase + (kt + 1) * BK;

    v8h zrn[4];
    float zv[32];
    float4 xq_n = (float4){0.f, 0.f, 0.f, 0.f};
    if (have_next){
      if (PRE){
        #pragma unroll
        for (int i = 0; i < 4; ++i)
          zrn[i] = *(const v8h*)&ztg[(kt + 1) * BK + 8 * i];
      } else {
        #pragma unroll
        for (int i = 0; i < 32; ++i)
          zv[i] = zb[(size_t)(n1 + zkh * 32 + i) * DZc + zd];
      }
      xq_n = *(const float4*)&xb[(size_t)(n1 + 2 * gp) * 2];
    }

    #pragma unroll
    for (int kstep = 0; kstep < 4; ++kstep){
      const int k0 = kstep * 16 + lh * 8;
      const v8h xu = *(const v8h*)&gt[buf][gxr][k0];
      v8h bfr[4];
      #pragma unroll
      for (int dtl = 0; dtl < 4; ++dtl){
        union { v4h h[2]; v8h v; } zu;
        zu.h[0] = *(const v4h*)&zt[buf][dtl * 32 + l31][k0];
        zu.h[1] = *(const v4h*)&zt[buf][dtl * 32 + l31][k0 + 4];
        bfr[dtl] = zu.v;
      }
      #pragma unroll
      for (int mtl = 0; mtl < 2; ++mtl){
        const v8h yu = *(const v8h*)&gt[buf][gyr + mtl * 4][k0];
        v8h av = yu * xu;   // 4x v_pk_mul_f16
        #pragma unroll
        for (int dtl = 0; dtl < 4; ++dtl)
          acc[mtl][dtl] = __builtin_amdgcn_mfma_f32_32x32x16_f16(av, bfr[dtl], acc[mtl][dtl], 0, 0, 0);
      }
    }

    if (have_next){
      if (PRE){
        #pragma unroll
        for (int i = 0; i < 4; ++i){
          union { v8h v; double d[2]; } u;
          u.v = zrn[i];
          *(double*)&zt[nbuf][zd][zkh * 32 + 8 * i]     = u.d[0];
          *(double*)&zt[nbuf][zd][zkh * 32 + 8 * i + 4] = u.d[1];
        }
      } else {
        #pragma unroll
        for (int j = 0; j < 8; ++j){
          union { unsigned u[2]; double d; } w;
          w.u[0] = pk16(zv[4 * j],     zv[4 * j + 1]);
          w.u[1] = pk16(zv[4 * j + 2], zv[4 * j + 3]);
          *(double*)&zt[nbuf][zd][zkh * 32 + 4 * j] = w.d;
        }
      }
      unsigned* gw = (unsigned*)&gt[nbuf][0][0];
      #pragma unroll
      for (int i = 0; i < 5; ++i){
        int row = gr + 8 * i;
        float s0 = (row < 32) ? xq_n.x : xq_n.y;
        float s1 = (row < 32) ? xq_n.z : xq_n.w;
        float d0 = gc[i] - s0, d1 = gc[i] - s1;
        gw[row * 36 + gp] = pk16(fexp2(ga[i] * d0 * d0), fexp2(ga[i] * d1 * d1));
      }
    }
    __syncthreads();
  }

  // ---- epilogue: direct f32 atomic accumulate into out
  // C/D of 32x32: col = lane&31 (d), row = (reg&3) + 8*(reg>>2) + 4*(lane>>5)
  #pragma unroll
  for (int mtl = 0; mtl < 2; ++mtl)
    #pragma unroll
    for (int dtl = 0; dtl < 4; ++dtl){
      const int d = dtl * 32 + l31;
      #pragma unroll
      for (int reg = 0; reg < 16; ++reg){
        const int row = (reg & 3) + 8 * (reg >> 2) + 4 * lh;
        const int m = wv * 64 + mtl * 32 + row;
        const int iy = iy0 + (m >> 3);
        const int ix = ix0 + (m & 7);
        unsafeAtomicAdd(&out[((b * HH + iy) * WW + ix) * DZc + d], acc[mtl][dtl][reg]);
      }
    }
}

extern "C" void kernel_launch(void* const* d_in, const int* in_sizes, int n_in,
                              void* d_out, int out_size, void* d_ws, size_t ws_size,
                              hipStream_t stream){
  const float* xc_off = (const float*)d_in[0];
  const float* xc_on  = (const float*)d_in[1];
  const float* zc_off = (const float*)d_in[2];
  const float* zc_on  = (const float*)d_in[3];
  const float* lsp    = (const float*)d_in[4];
  const int*   ign    = (const int*)d_in[5];
  float* out = (float*)d_out;

  // out = zc_on (or 0); 2048 blocks covers CELLS floats as float4.
  init_out_kernel<<<CELLS / 4 / 256, 256, 0, stream>>>((const float4*)zc_on, ign, (float4*)out);

  if (ws_size >= ZT_BYTES){
    _Float16* zpack = (_Float16*)d_ws;
    prepack_kernel<<<4 * 64, 256, 0, stream>>>(zc_off, zpack);
    setconv_gemm_kernel<true><<<KS * 64, 256, 0, stream>>>(xc_off, xc_on, zc_off, zpack, lsp, out);
  } else {
    setconv_gemm_kernel<false><<<KS * 64, 256, 0, stream>>>(xc_off, xc_on, zc_off, nullptr, lsp, out);
  }
}

// Round 5
// 106.943 us; speedup vs baseline: 1.4495x; 1.3427x over previous
//
#include <hip/hip_runtime.h>

#define HH 64
#define WW 64
#define NN 4096
#define DZc 128
#define KS 8
#define BK 64
#define NKT (NN / KS / BK)        // 8 k-tiles per block
#define CELLS 2097152             // 4*64*64*128 output floats
#define ZT_BYTES (4ull * 128 * 4096 * 2ull)            // packed zT f16: 4 MB
#define WS_NEED (ZT_BYTES + 8ull * CELLS * 2ull)       // zT + f16 partials: 36 MB

typedef __fp16 v2fp16 __attribute__((ext_vector_type(2)));
typedef _Float16 v4h __attribute__((ext_vector_type(4)));
typedef _Float16 v8h __attribute__((ext_vector_type(8)));
typedef float v16f __attribute__((ext_vector_type(16)));
typedef double v2d __attribute__((ext_vector_type(2)));

__device__ __forceinline__ unsigned pk16(float lo, float hi){
  union { v2fp16 h; unsigned u; } c;
  c.h = __builtin_amdgcn_cvt_pkrtz(lo, hi);
  return c.u;
}
__device__ __forceinline__ float fexp2(float x){ return __builtin_amdgcn_exp2f(x); }

// out = zc_on (or 0 if ignore). Only used on the no-ws fallback path.
__global__ __launch_bounds__(256, 8)
void init_out_kernel(const float4* __restrict__ zc_on,
                     const int* __restrict__ ignore,
                     float4* __restrict__ out){
  int i = blockIdx.x * blockDim.x + threadIdx.x;
  float4 v = zc_on[i];
  if (ignore[0]) { v.x = 0.f; v.y = 0.f; v.z = 0.f; v.w = 0.f; }
  out[i] = v;
}

// transpose+pack z once: f32 [B][N][128] -> f16 zT [B][128][N]. (~2 us measured)
__global__ __launch_bounds__(256, 4)
void prepack_kernel(const float* __restrict__ zc_off, _Float16* __restrict__ zt_g){
  __shared__ unsigned tt[128 * 34];   // [d][n-pair] dwords, row stride 34 dw (68 f16)
  const int bidx = blockIdx.x;
  const int b  = bidx >> 6;
  const int n0 = (bidx & 63) * 64;
  const int t  = threadIdx.x;

  const int np = t >> 3;
  const int d0 = (t & 7) * 16;
  const float* r0 = zc_off + ((size_t)(b * NN + n0 + 2 * np)) * DZc + d0;
  float4 a[4], c[4];
  #pragma unroll
  for (int i = 0; i < 4; ++i){
    a[i] = *(const float4*)&r0[4 * i];
    c[i] = *(const float4*)&r0[DZc + 4 * i];
  }
  const float* af = (const float*)a;
  const float* cf = (const float*)c;
  #pragma unroll
  for (int j = 0; j < 16; ++j)
    tt[(d0 + j) * 34 + np] = pk16(af[j], cf[j]);

  __syncthreads();

  const int d  = t >> 1;
  const int nh = t & 1;
  const unsigned* rr = tt + d * 34 + nh * 16;
  _Float16* w = zt_g + ((size_t)(b * DZc + d)) * NN + n0 + nh * 32;
  double v[8];
  #pragma unroll
  for (int j = 0; j < 8; ++j) v[j] = *(const double*)&rr[2 * j];
  #pragma unroll
  for (int j = 0; j < 4; ++j){
    v2d s; s[0] = v[2 * j]; s[1] = v[2 * j + 1];
    *(v2d*)&w[8 * j] = s;
  }
}

// sum 8 f16 K-split partials + zc_on -> out.
// v2: b128 partial loads (v8h), 8 cells/thread -> half the instruction count of v1.
// 48 MB total traffic; target ~9 us (was 13.2 inferred).
__global__ __launch_bounds__(256, 8)
void reduce_kernel(const v8h* __restrict__ part,
                   const float4* __restrict__ zc_on,
                   const int* __restrict__ ignore,
                   float4* __restrict__ out){
  int i = blockIdx.x * blockDim.x + threadIdx.x;   // [0, CELLS/8)
  float4 s0 = zc_on[2 * i];
  float4 s1 = zc_on[2 * i + 1];
  if (ignore[0]) {
    s0.x = s0.y = s0.z = s0.w = 0.f;
    s1.x = s1.y = s1.z = s1.w = 0.f;
  }
  #pragma unroll
  for (int ks = 0; ks < KS; ++ks){
    v8h p = part[(size_t)ks * (CELLS / 8) + i];
    s0.x += (float)p[0]; s0.y += (float)p[1]; s0.z += (float)p[2]; s0.w += (float)p[3];
    s1.x += (float)p[4]; s1.y += (float)p[5]; s1.z += (float)p[6]; s1.w += (float)p[7];
  }
  out[2 * i]     = s0;
  out[2 * i + 1] = s1;
}

// Grid: 512 blocks = ks(8, HIGH bits) x b(4) x mt(16).
// Block: 256 thr = 4 waves; BM=256 (32iy x 8ix), BD=128, BK=64, 8 k-tiles.
// Wave: 64m x 128d via 2x4 tiles of 32x32x16 f16 MFMA.
// k-loop: [loads kt+1] [setprio(1) consume 4 ksteps setprio(0)] [write Z kt+1]
//         [gtab kt+1] [barrier] -> Z vmcnt wait covered by the full consume phase.
// Epilogue: f16 partial stores to ws (measured G=22.7us; atomics cost +44us, rejected).
template<bool PRE>
__global__ __launch_bounds__(256, 2)
void setconv_gemm_kernel(const float* __restrict__ xc_off,
                         const float* __restrict__ xc_on,
                         const float* __restrict__ zc_off,
                         const _Float16* __restrict__ zpack,
                         const float* __restrict__ lsp,
                         _Float16* __restrict__ part,
                         float* __restrict__ out)
{
  __shared__ unsigned short zt[2][128][68];  // Z^T f16 [d][k], stride 34 dw (0 conflicts measured)
  __shared__ unsigned short gt[2][40][72];   // f16 g-tables, stride 36 dw

  const int tid = threadIdx.x;
  const int bid = blockIdx.x;
  const int ks  = bid >> 6;
  const int bm  = bid & 63;
  const int b   = bm >> 4;
  const int mt  = bm & 15;
  const int iy0 = (mt >> 3) * 32;
  const int ix0 = (mt & 7) * 8;
  const int nbase = ks * (NN / KS);

  const float lsy = 1e-5f + log1pf(expf(lsp[0]));
  const float lsx = 1e-5f + log1pf(expf(lsp[1]));
  const float LOG2E = 1.44269504088896340736f;
  const float ay = -0.5f * LOG2E / (lsy * lsy);
  const float ax = -0.5f * LOG2E / (lsx * lsx);

  const int gp = tid & 31;
  const int gr = tid >> 5;
  float gc[5], ga[5];
  #pragma unroll
  for (int i = 0; i < 5; ++i){
    int row = gr + 8 * i;
    if (row < 32){ gc[i] = xc_on[((b * HH + iy0 + row) * WW) * 2];        ga[i] = ay; }
    else         { gc[i] = xc_on[(b * HH * WW + ix0 + row - 32) * 2 + 1]; ga[i] = ax; }
  }

  const int zd  = (tid & 63) | (((tid >> 6) & 1) << 6);
  const int zkh = tid >> 7;
  const _Float16* ztg = PRE ? (zpack + ((size_t)(b * DZc + zd)) * NN + nbase + zkh * 32)
                            : (const _Float16*)nullptr;

  const int lane = tid & 63;
  const int wv  = tid >> 6;
  const int l31 = lane & 31;
  const int lh  = lane >> 5;
  const int gxr = 32 + (l31 & 7);
  const int gyr = wv * 8 + (l31 >> 3);

  v16f acc[2][4];
  #pragma unroll
  for (int m = 0; m < 2; ++m)
    #pragma unroll
    for (int d = 0; d < 4; ++d)
      #pragma unroll
      for (int r = 0; r < 16; ++r)
        acc[m][d][r] = 0.f;

  const float* xb = xc_off + (size_t)b * NN * 2;
  const float* zb = zc_off + (size_t)b * NN * DZc;

  {
    const int n0 = nbase;
    float4 xq = *(const float4*)&xb[(size_t)(n0 + 2 * gp) * 2];
    unsigned* gw = (unsigned*)&gt[0][0][0];
    #pragma unroll
    for (int i = 0; i < 5; ++i){
      int row = gr + 8 * i;
      float s0 = (row < 32) ? xq.x : xq.y;
      float s1 = (row < 32) ? xq.z : xq.w;
      float d0 = gc[i] - s0, d1 = gc[i] - s1;
      gw[row * 36 + gp] = pk16(fexp2(ga[i] * d0 * d0), fexp2(ga[i] * d1 * d1));
    }
    if (PRE){
      #pragma unroll
      for (int i = 0; i < 4; ++i){
        union { v8h v; double d[2]; } u;
        u.v = *(const v8h*)&ztg[8 * i];
        *(double*)&zt[0][zd][zkh * 32 + 8 * i]     = u.d[0];
        *(double*)&zt[0][zd][zkh * 32 + 8 * i + 4] = u.d[1];
      }
    } else {
      float zv[32];
      #pragma unroll
      for (int i = 0; i < 32; ++i)
        zv[i] = zb[(size_t)(n0 + zkh * 32 + i) * DZc + zd];
      #pragma unroll
      for (int j = 0; j < 8; ++j){
        union { unsigned u[2]; double d; } w;
        w.u[0] = pk16(zv[4 * j],     zv[4 * j + 1]);
        w.u[1] = pk16(zv[4 * j + 2], zv[4 * j + 3]);
        *(double*)&zt[0][zd][zkh * 32 + 4 * j] = w.d;
      }
    }
  }
  __syncthreads();

  #pragma unroll 1
  for (int kt = 0; kt < NKT; ++kt){
    const int buf  = kt & 1;
    const int nbuf = buf ^ 1;
    const bool have_next = (kt + 1 < NKT);
    const int n1 = nbase + (kt + 1) * BK;

    v8h zrn[4];
    float zv[32];
    float4 xq_n = (float4){0.f, 0.f, 0.f, 0.f};
    if (have_next){
      if (PRE){
        #pragma unroll
        for (int i = 0; i < 4; ++i)
          zrn[i] = *(const v8h*)&ztg[(kt + 1) * BK + 8 * i];
      } else {
        #pragma unroll
        for (int i = 0; i < 32; ++i)
          zv[i] = zb[(size_t)(n1 + zkh * 32 + i) * DZc + zd];
      }
      xq_n = *(const float4*)&xb[(size_t)(n1 + 2 * gp) * 2];
    }

    // ---- consume all 4 ksteps, wave priority boosted across the MFMA cluster
    __builtin_amdgcn_s_setprio(1);
    #pragma unroll
    for (int kstep = 0; kstep < 4; ++kstep){
      const int k0 = kstep * 16 + lh * 8;
      const v8h xu = *(const v8h*)&gt[buf][gxr][k0];
      v8h bfr[4];
      #pragma unroll
      for (int dtl = 0; dtl < 4; ++dtl){
        union { v4h h[2]; v8h v; } zu;
        zu.h[0] = *(const v4h*)&zt[buf][dtl * 32 + l31][k0];
        zu.h[1] = *(const v4h*)&zt[buf][dtl * 32 + l31][k0 + 4];
        bfr[dtl] = zu.v;
      }
      #pragma unroll
      for (int mtl = 0; mtl < 2; ++mtl){
        const v8h yu = *(const v8h*)&gt[buf][gyr + mtl * 4][k0];
        v8h av = yu * xu;   // 4x v_pk_mul_f16
        #pragma unroll
        for (int dtl = 0; dtl < 4; ++dtl)
          acc[mtl][dtl] = __builtin_amdgcn_mfma_f32_32x32x16_f16(av, bfr[dtl], acc[mtl][dtl], 0, 0, 0);
      }
    }
    __builtin_amdgcn_s_setprio(0);

    if (have_next){
      if (PRE){
        #pragma unroll
        for (int i = 0; i < 4; ++i){
          union { v8h v; double d[2]; } u;
          u.v = zrn[i];
          *(double*)&zt[nbuf][zd][zkh * 32 + 8 * i]     = u.d[0];
          *(double*)&zt[nbuf][zd][zkh * 32 + 8 * i + 4] = u.d[1];
        }
      } else {
        #pragma unroll
        for (int j = 0; j < 8; ++j){
          union { unsigned u[2]; double d; } w;
          w.u[0] = pk16(zv[4 * j],     zv[4 * j + 1]);
          w.u[1] = pk16(zv[4 * j + 2], zv[4 * j + 3]);
          *(double*)&zt[nbuf][zd][zkh * 32 + 4 * j] = w.d;
        }
      }
      unsigned* gw = (unsigned*)&gt[nbuf][0][0];
      #pragma unroll
      for (int i = 0; i < 5; ++i){
        int row = gr + 8 * i;
        float s0 = (row < 32) ? xq_n.x : xq_n.y;
        float s1 = (row < 32) ? xq_n.z : xq_n.w;
        float d0 = gc[i] - s0, d1 = gc[i] - s1;
        gw[row * 36 + gp] = pk16(fexp2(ga[i] * d0 * d0), fexp2(ga[i] * d1 * d1));
      }
    }
    __syncthreads();
  }

  // ---- epilogue
  // C/D of 32x32: col = lane&31 (d), row = (reg&3) + 8*(reg>>2) + 4*(lane>>5)
  if (part){
    _Float16* pw = part + (size_t)ks * CELLS;
    #pragma unroll
    for (int mtl = 0; mtl < 2; ++mtl)
      #pragma unroll
      for (int dtl = 0; dtl < 4; ++dtl){
        const int d = dtl * 32 + l31;
        #pragma unroll
        for (int reg = 0; reg < 16; ++reg){
          const int row = (reg & 3) + 8 * (reg >> 2) + 4 * lh;
          const int m = wv * 64 + mtl * 32 + row;
          const int iy = iy0 + (m >> 3);
          const int ix = ix0 + (m & 7);
          pw[((b * HH + iy) * WW + ix) * DZc + d] = (_Float16)acc[mtl][dtl][reg];
        }
      }
  } else {
    #pragma unroll
    for (int mtl = 0; mtl < 2; ++mtl)
      #pragma unroll
      for (int dtl = 0; dtl < 4; ++dtl){
        const int d = dtl * 32 + l31;
        #pragma unroll
        for (int reg = 0; reg < 16; ++reg){
          const int row = (reg & 3) + 8 * (reg >> 2) + 4 * lh;
          const int m = wv * 64 + mtl * 32 + row;
          const int iy = iy0 + (m >> 3);
          const int ix = ix0 + (m & 7);
          unsafeAtomicAdd(&out[((b * HH + iy) * WW + ix) * DZc + d], acc[mtl][dtl][reg]);
        }
      }
  }
}

extern "C" void kernel_launch(void* const* d_in, const int* in_sizes, int n_in,
                              void* d_out, int out_size, void* d_ws, size_t ws_size,
                              hipStream_t stream){
  const float* xc_off = (const float*)d_in[0];
  const float* xc_on  = (const float*)d_in[1];
  const float* zc_off = (const float*)d_in[2];
  const float* zc_on  = (const float*)d_in[3];
  const float* lsp    = (const float*)d_in[4];
  const int*   ign    = (const int*)d_in[5];
  float* out = (float*)d_out;

  if (ws_size >= WS_NEED){
    _Float16* zpack = (_Float16*)d_ws;
    _Float16* part  = (_Float16*)((char*)d_ws + ZT_BYTES);
    prepack_kernel<<<4 * 64, 256, 0, stream>>>(zc_off, zpack);
    setconv_gemm_kernel<true><<<KS * 64, 256, 0, stream>>>(xc_off, xc_on, zc_off, zpack, lsp, part, out);
    reduce_kernel<<<CELLS / 8 / 256, 256, 0, stream>>>((const v8h*)part, (const float4*)zc_on, ign, (float4*)out);
  } else {
    init_out_kernel<<<CELLS / 4 / 256, 256, 0, stream>>>((const float4*)zc_on, ign, (float4*)out);
    setconv_gemm_kernel<false><<<KS * 64, 256, 0, stream>>>(xc_off, xc_on, zc_off, nullptr, lsp, nullptr, out);
  }
}

// Round 7
// 105.091 us; speedup vs baseline: 1.4751x; 1.0176x over previous
//
#include <hip/hip_runtime.h>

#define HH 64
#define WW 64
#define NN 4096
#define DZc 128
#define KS 8
#define BK 64
#define NKT (NN / KS / BK)        // 8 k-tiles per block
#define CELLS 2097152             // 4*64*64*128 output floats
#define ZT_BYTES (4ull * 128 * 4096 * 2ull)            // packed zT f16: 4 MB
#define WS_NEED (ZT_BYTES + 8ull * CELLS * 2ull)       // zT + f16 partials: 36 MB

typedef __fp16 v2fp16 __attribute__((ext_vector_type(2)));
typedef _Float16 v4h __attribute__((ext_vector_type(4)));
typedef _Float16 v8h __attribute__((ext_vector_type(8)));
typedef float v16f __attribute__((ext_vector_type(16)));
typedef double v2d __attribute__((ext_vector_type(2)));

__device__ __forceinline__ unsigned pk16(float lo, float hi){
  union { v2fp16 h; unsigned u; } c;
  c.h = __builtin_amdgcn_cvt_pkrtz(lo, hi);
  return c.u;
}
__device__ __forceinline__ float fexp2(float x){ return __builtin_amdgcn_exp2f(x); }

// out = zc_on (or 0 if ignore). Only used on the no-ws fallback path.
__global__ __launch_bounds__(256, 8)
void init_out_kernel(const float4* __restrict__ zc_on,
                     const int* __restrict__ ignore,
                     float4* __restrict__ out){
  int i = blockIdx.x * blockDim.x + threadIdx.x;
  float4 v = zc_on[i];
  if (ignore[0]) { v.x = 0.f; v.y = 0.f; v.z = 0.f; v.w = 0.f; }
  out[i] = v;
}

// transpose+pack z once: f32 [B][N][128] -> f16 zT [B][128][N]. (~2 us measured)
__global__ __launch_bounds__(256, 4)
void prepack_kernel(const float* __restrict__ zc_off, _Float16* __restrict__ zt_g){
  __shared__ unsigned tt[128 * 34];   // [d][n-pair] dwords, row stride 34 dw (68 f16)
  const int bidx = blockIdx.x;
  const int b  = bidx >> 6;
  const int n0 = (bidx & 63) * 64;
  const int t  = threadIdx.x;

  const int np = t >> 3;
  const int d0 = (t & 7) * 16;
  const float* r0 = zc_off + ((size_t)(b * NN + n0 + 2 * np)) * DZc + d0;
  float4 a[4], c[4];
  #pragma unroll
  for (int i = 0; i < 4; ++i){
    a[i] = *(const float4*)&r0[4 * i];
    c[i] = *(const float4*)&r0[DZc + 4 * i];
  }
  const float* af = (const float*)a;
  const float* cf = (const float*)c;
  #pragma unroll
  for (int j = 0; j < 16; ++j)
    tt[(d0 + j) * 34 + np] = pk16(af[j], cf[j]);

  __syncthreads();

  const int d  = t >> 1;
  const int nh = t & 1;
  const unsigned* rr = tt + d * 34 + nh * 16;
  _Float16* w = zt_g + ((size_t)(b * DZc + d)) * NN + n0 + nh * 32;
  double v[8];
  #pragma unroll
  for (int j = 0; j < 8; ++j) v[j] = *(const double*)&rr[2 * j];
  #pragma unroll
  for (int j = 0; j < 4; ++j){
    v2d s; s[0] = v[2 * j]; s[1] = v[2 * j + 1];
    *(v2d*)&w[8 * j] = s;
  }
}

// sum 8 f16 K-split partials + zc_on -> out (b128 loads, 8 cells/thread).
__global__ __launch_bounds__(256, 8)
void reduce_kernel(const v8h* __restrict__ part,
                   const float4* __restrict__ zc_on,
                   const int* __restrict__ ignore,
                   float4* __restrict__ out){
  int i = blockIdx.x * blockDim.x + threadIdx.x;   // [0, CELLS/8)
  float4 s0 = zc_on[2 * i];
  float4 s1 = zc_on[2 * i + 1];
  if (ignore[0]) {
    s0.x = s0.y = s0.z = s0.w = 0.f;
    s1.x = s1.y = s1.z = s1.w = 0.f;
  }
  #pragma unroll
  for (int ks = 0; ks < KS; ++ks){
    v8h p = part[(size_t)ks * (CELLS / 8) + i];
    s0.x += (float)p[0]; s0.y += (float)p[1]; s0.z += (float)p[2]; s0.w += (float)p[3];
    s1.x += (float)p[4]; s1.y += (float)p[5]; s1.z += (float)p[6]; s1.w += (float)p[7];
  }
  out[2 * i]     = s0;
  out[2 * i + 1] = s1;
}

// Grid: 512 blocks = ks(8, HIGH bits) x b(4) x mt(16).
// Block: 512 thr = 8 waves (was 4); BM=256, BD=128, BK=64, 8 k-tiles.
// Wave quadrant: mq = wv>>1 (64 m-rows), dh = wv&1 (64 d-cols) -> 2x2 tiles of
// 32x32x16 MFMA. Occupancy 8 -> 16 waves/CU (R4 counters: MfmaUtil 9.5%,
// VALUBusy 8.3%, no pipe saturated at 2 waves/SIMD => latency-bound; this
// doubles the waves available to hide LDS/MFMA dependency stalls).
// k-loop unchanged: [loads kt+1][setprio(1) consume setprio(0)][write kt+1][barrier].
template<bool PRE>
__global__ __launch_bounds__(512, 4)
void setconv_gemm_kernel(const float* __restrict__ xc_off,
                         const float* __restrict__ xc_on,
                         const float* __restrict__ zc_off,
                         const _Float16* __restrict__ zpack,
                         const float* __restrict__ lsp,
                         _Float16* __restrict__ part,
                         float* __restrict__ out)
{
  __shared__ unsigned short zt[2][128][68];  // Z^T f16 [d][k], stride 34 dw (0 conflicts measured)
  __shared__ unsigned short gt[2][40][72];   // f16 g-tables, stride 36 dw

  const int tid = threadIdx.x;
  const int bid = blockIdx.x;
  const int ks  = bid >> 6;
  const int bm  = bid & 63;
  const int b   = bm >> 4;
  const int mt  = bm & 15;
  const int iy0 = (mt >> 3) * 32;
  const int ix0 = (mt & 7) * 8;
  const int nbase = ks * (NN / KS);

  const float lsy = 1e-5f + log1pf(expf(lsp[0]));
  const float lsx = 1e-5f + log1pf(expf(lsp[1]));
  const float LOG2E = 1.44269504088896340736f;
  const float ay = -0.5f * LOG2E / (lsy * lsy);
  const float ax = -0.5f * LOG2E / (lsx * lsx);

  // ---- gtab staging: 40 rows x 32 col-pairs; thread -> col-pair gp, rows gr+16i (i<3, row<40)
  const int gp = tid & 31;
  const int gr = tid >> 5;            // 0..15
  float gc[3], ga[3];
  #pragma unroll
  for (int i = 0; i < 3; ++i){
    int row = gr + 16 * i;
    if (row < 32)      { gc[i] = xc_on[((b * HH + iy0 + row) * WW) * 2];        ga[i] = ay; }
    else if (row < 40) { gc[i] = xc_on[(b * HH * WW + ix0 + row - 32) * 2 + 1]; ga[i] = ax; }
    else               { gc[i] = 0.f; ga[i] = 0.f; }
  }

  // ---- Z staging: thread owns d-row zd (0..127), k-quarter zq (16 k each)
  const int zd = tid & 127;
  const int zq = tid >> 7;            // 0..3
  const _Float16* ztg = PRE ? (zpack + ((size_t)(b * DZc + zd)) * NN + nbase + zq * 16)
                            : (const _Float16*)nullptr;

  // ---- consumer mapping: 8 waves, wave = (mq, dh) quadrant of 64m x 64d
  const int lane = tid & 63;
  const int wv  = tid >> 6;
  const int mq  = wv >> 1;            // 0..3: m base mq*64
  const int dh  = wv & 1;             // 0..1: d base dh*64
  const int l31 = lane & 31;
  const int lh  = lane >> 5;
  const int gxr = 32 + (l31 & 7);
  const int gyr = mq * 8 + (l31 >> 3);     // + mtl*4
  const int dbase = dh * 64;

  v16f acc[2][2];
  #pragma unroll
  for (int m = 0; m < 2; ++m)
    #pragma unroll
    for (int d = 0; d < 2; ++d)
      #pragma unroll
      for (int r = 0; r < 16; ++r)
        acc[m][d][r] = 0.f;

  const float* xb = xc_off + (size_t)b * NN * 2;
  const float* zb = zc_off + (size_t)b * NN * DZc;

  // ---- prologue: stage k-tile 0 into buf 0
  {
    const int n0 = nbase;
    float4 xq = *(const float4*)&xb[(size_t)(n0 + 2 * gp) * 2];
    unsigned* gw = (unsigned*)&gt[0][0][0];
    #pragma unroll
    for (int i = 0; i < 3; ++i){
      int row = gr + 16 * i;
      if (row < 40){
        float s0 = (row < 32) ? xq.x : xq.y;
        float s1 = (row < 32) ? xq.z : xq.w;
        float d0 = gc[i] - s0, d1 = gc[i] - s1;
        gw[row * 36 + gp] = pk16(fexp2(ga[i] * d0 * d0), fexp2(ga[i] * d1 * d1));
      }
    }
    if (PRE){
      #pragma unroll
      for (int i = 0; i < 2; ++i){
        union { v8h v; double d[2]; } u;
        u.v = *(const v8h*)&ztg[8 * i];
        *(double*)&zt[0][zd][zq * 16 + 8 * i]     = u.d[0];
        *(double*)&zt[0][zd][zq * 16 + 8 * i + 4] = u.d[1];
      }
    } else {
      float zv[16];
      #pragma unroll
      for (int i = 0; i < 16; ++i)
        zv[i] = zb[(size_t)(n0 + zq * 16 + i) * DZc + zd];
      #pragma unroll
      for (int j = 0; j < 4; ++j){
        union { unsigned u[2]; double d; } w;
        w.u[0] = pk16(zv[4 * j],     zv[4 * j + 1]);
        w.u[1] = pk16(zv[4 * j + 2], zv[4 * j + 3]);
        *(double*)&zt[0][zd][zq * 16 + 4 * j] = w.d;
      }
    }
  }
  __syncthreads();

  #pragma unroll 1
  for (int kt = 0; kt < NKT; ++kt){
    const int buf  = kt & 1;
    const int nbuf = buf ^ 1;
    const bool have_next = (kt + 1 < NKT);
    const int n1 = nbase + (kt + 1) * BK;

    // ---- issue next tile's global loads (drain across the whole consume phase)
    v8h zrn[2];
    float zv[16];
    float4 xq_n = (float4){0.f, 0.f, 0.f, 0.f};
    if (have_next){
      if (PRE){
        #pragma unroll
        for (int i = 0; i < 2; ++i)
          zrn[i] = *(const v8h*)&ztg[(kt + 1) * BK + 8 * i];
      } else {
        #pragma unroll
        for (int i = 0; i < 16; ++i)
          zv[i] = zb[(size_t)(n1 + zq * 16 + i) * DZc + zd];
      }
      xq_n = *(const float4*)&xb[(size_t)(n1 + 2 * gp) * 2];
    }

    // ---- consume all 4 ksteps, wave priority boosted across the MFMA cluster
    __builtin_amdgcn_s_setprio(1);
    #pragma unroll
    for (int kstep = 0; kstep < 4; ++kstep){
      const int k0 = kstep * 16 + lh * 8;
      const v8h xu = *(const v8h*)&gt[buf][gxr][k0];
      v8h bfr[2];
      #pragma unroll
      for (int dtl = 0; dtl < 2; ++dtl){
        union { v4h h[2]; v8h v; } zu;
        zu.h[0] = *(const v4h*)&zt[buf][dbase + dtl * 32 + l31][k0];
        zu.h[1] = *(const v4h*)&zt[buf][dbase + dtl * 32 + l31][k0 + 4];
        bfr[dtl] = zu.v;
      }
      #pragma unroll
      for (int mtl = 0; mtl < 2; ++mtl){
        const v8h yu = *(const v8h*)&gt[buf][gyr + mtl * 4][k0];
        v8h av = yu * xu;   // 4x v_pk_mul_f16
        #pragma unroll
        for (int dtl = 0; dtl < 2; ++dtl)
          acc[mtl][dtl] = __builtin_amdgcn_mfma_f32_32x32x16_f16(av, bfr[dtl], acc[mtl][dtl], 0, 0, 0);
      }
    }
    __builtin_amdgcn_s_setprio(0);

    // ---- write next tile to LDS (vmcnt wait lands here, after full consume)
    if (have_next){
      if (PRE){
        #pragma unroll
        for (int i = 0; i < 2; ++i){
          union { v8h v; double d[2]; } u;
          u.v = zrn[i];
          *(double*)&zt[nbuf][zd][zq * 16 + 8 * i]     = u.d[0];
          *(double*)&zt[nbuf][zd][zq * 16 + 8 * i + 4] = u.d[1];
        }
      } else {
        #pragma unroll
        for (int j = 0; j < 4; ++j){
          union { unsigned u[2]; double d; } w;
          w.u[0] = pk16(zv[4 * j],     zv[4 * j + 1]);
          w.u[1] = pk16(zv[4 * j + 2], zv[4 * j + 3]);
          *(double*)&zt[nbuf][zd][zq * 16 + 4 * j] = w.d;
        }
      }
      unsigned* gw = (unsigned*)&gt[nbuf][0][0];
      #pragma unroll
      for (int i = 0; i < 3; ++i){
        int row = gr + 16 * i;
        if (row < 40){
          float s0 = (row < 32) ? xq_n.x : xq_n.y;
          float s1 = (row < 32) ? xq_n.z : xq_n.w;
          float d0 = gc[i] - s0, d1 = gc[i] - s1;
          gw[row * 36 + gp] = pk16(fexp2(ga[i] * d0 * d0), fexp2(ga[i] * d1 * d1));
        }
      }
    }
    __syncthreads();
  }

  // ---- epilogue
  // C/D of 32x32: col = lane&31 (d), row = (reg&3) + 8*(reg>>2) + 4*(lane>>5)
  if (part){
    _Float16* pw = part + (size_t)ks * CELLS;
    #pragma unroll
    for (int mtl = 0; mtl < 2; ++mtl)
      #pragma unroll
      for (int dtl = 0; dtl < 2; ++dtl){
        const int d = dbase + dtl * 32 + l31;
        #pragma unroll
        for (int reg = 0; reg < 16; ++reg){
          const int row = (reg & 3) + 8 * (reg >> 2) + 4 * lh;
          const int m = mq * 64 + mtl * 32 + row;
          const int iy = iy0 + (m >> 3);
          const int ix = ix0 + (m & 7);
          pw[((b * HH + iy) * WW + ix) * DZc + d] = (_Float16)acc[mtl][dtl][reg];
        }
      }
  } else {
    #pragma unroll
    for (int mtl = 0; mtl < 2; ++mtl)
      #pragma unroll
      for (int dtl = 0; dtl < 2; ++dtl){
        const int d = dbase + dtl * 32 + l31;
        #pragma unroll
        for (int reg = 0; reg < 16; ++reg){
          const int row = (reg & 3) + 8 * (reg >> 2) + 4 * lh;
          const int m = mq * 64 + mtl * 32 + row;
          const int iy = iy0 + (m >> 3);
          const int ix = ix0 + (m & 7);
          unsafeAtomicAdd(&out[((b * HH + iy) * WW + ix) * DZc + d], acc[mtl][dtl][reg]);
        }
      }
  }
}

extern "C" void kernel_launch(void* const* d_in, const int* in_sizes, int n_in,
                              void* d_out, int out_size, void* d_ws, size_t ws_size,
                              hipStream_t stream){
  const float* xc_off = (const float*)d_in[0];
  const float* xc_on  = (const float*)d_in[1];
  const float* zc_off = (const float*)d_in[2];
  const float* zc_on  = (const float*)d_in[3];
  const float* lsp    = (const float*)d_in[4];
  const int*   ign    = (const int*)d_in[5];
  float* out = (float*)d_out;

  if (ws_size >= WS_NEED){
    _Float16* zpack = (_Float16*)d_ws;
    _Float16* part  = (_Float16*)((char*)d_ws + ZT_BYTES);
    prepack_kernel<<<4 * 64, 256, 0, stream>>>(zc_off, zpack);
    setconv_gemm_kernel<true><<<KS * 64, 512, 0, stream>>>(xc_off, xc_on, zc_off, zpack, lsp, part, out);
    reduce_kernel<<<CELLS / 8 / 256, 256, 0, stream>>>((const v8h*)part, (const float4*)zc_on, ign, (float4*)out);
  } else {
    init_out_kernel<<<CELLS / 4 / 256, 256, 0, stream>>>((const float4*)zc_on, ign, (float4*)out);
    setconv_gemm_kernel<false><<<KS * 64, 512, 0, stream>>>(xc_off, xc_on, zc_off, nullptr, lsp, nullptr, out);
  }
}